// Round 9
// baseline (176.085 us; speedup 1.0000x reference)
//
#include <hip/hip_runtime.h>

#define NTOK  16384   // B*T
#define KDIM  512
#define NQKV  1536
#define TT    4096

using frag8   = __attribute__((ext_vector_type(8))) short;
using floatx4 = __attribute__((ext_vector_type(4))) float;

__device__ __forceinline__ unsigned short f2b(float f) {
  union { float f; unsigned u; } v; v.f = f;
  unsigned r = v.u + 0x7fffu + ((v.u >> 16) & 1u);
  return (unsigned short)(r >> 16);
}
__device__ __forceinline__ float b2f(unsigned short s) {
  union { unsigned u; float f; } v; v.u = ((unsigned)s) << 16; return v.f;
}
__device__ __forceinline__ float blo(unsigned w) {
  union { unsigned u; float f; } v; v.u = w << 16; return v.f;
}
__device__ __forceinline__ float bhi(unsigned w) {
  union { unsigned u; float f; } v; v.u = w & 0xffff0000u; return v.f;
}

__device__ __forceinline__ void gl_lds16(const void* g, void* l) {
  __builtin_amdgcn_global_load_lds((__attribute__((address_space(1))) const void*)g,
                                   (__attribute__((address_space(3))) void*)l,
                                   16, 0, 0);
}
__device__ __forceinline__ floatx4 mfma16(frag8 a, frag8 b, floatx4 c) {
  return __builtin_amdgcn_mfma_f32_16x16x32_bf16(a, b, c, 0, 0, 0);
}

// ---------------- fused convert: x -> bf16, weights -> bf16 (float4), bias concat --------
__global__ __launch_bounds__(256) void cvt_all(
    const float* __restrict__ x,
    const float* __restrict__ Wq, const float* __restrict__ Wk,
    const float* __restrict__ Wv, const float* __restrict__ Wp,
    const float* __restrict__ bq, const float* __restrict__ bk,
    const float* __restrict__ bv,
    unsigned short* __restrict__ xb,
    unsigned short* __restrict__ wqkv, unsigned short* __restrict__ wp,
    float* __restrict__ bias_qkv) {
  const int blk = blockIdx.x;
  if (blk < 8192) {                          // x: 8.4M floats, float4 per thread
    const size_t i = (size_t)blk * 256 + threadIdx.x;
    const float4 v = ((const float4*)x)[i];
    ushort4 o;
    o.x = f2b(v.x); o.y = f2b(v.y); o.z = f2b(v.z); o.w = f2b(v.w);
    ((ushort4*)xb)[i] = o;
    return;
  }
  int idx = (blk - 8192) * 256 + threadIdx.x;
  if (idx < 196608) {                       // wqkv: 1536 rows x 128 float4
    const int m = idx >> 7, c4 = (idx & 127) << 2;
    const float* W = (m < 512) ? Wq : ((m < 1024) ? Wk : Wv);
    const float4 v = *(const float4*)&W[(m & 511) * 512 + c4];
    ushort4 o;
    o.x = f2b(v.x); o.y = f2b(v.y); o.z = f2b(v.z); o.w = f2b(v.w);
    *(ushort4*)&wqkv[m * 512 + c4] = o;
    return;
  }
  idx -= 196608;
  if (idx < 65536) {                        // wp: 65536 float4
    const float4 v = ((const float4*)Wp)[idx];
    ushort4 o;
    o.x = f2b(v.x); o.y = f2b(v.y); o.z = f2b(v.z); o.w = f2b(v.w);
    ((ushort4*)wp)[idx] = o;
    return;
  }
  idx -= 65536;
  if (idx < 1536)
    bias_qkv[idx] = (idx < 512) ? bq[idx]
                  : ((idx < 1024) ? bk[idx - 512] : bv[idx - 1024]);
}

// ---------------- bf16 GEMM, B^T input, XCD-swizzled, BK=64 + XOR LDS swizzle ----------------
// Geometry change only vs verified structure: BM=256, BN=128, 8 waves (512 thr),
// SAME single-buffered 2-barrier K-loop. FLOP per barrier/drain doubles; LDS 48 KB
// -> 3 blocks/CU (24 waves). Wave grid 4m x 2n, per-wave acc[4][4] unchanged.
// SOFT=1 epilogue by region (block-uniform, 512 % 128 == 0):
//   region 0 (q): softmax + padded-LDS repack -> C (q_buf, ldc=512), 4 passes
//   region 1 (k): softmax + TRANSPOSED repack -> kt[bh][64 d][4096 t], 2 passes
//   region 2 (v): TRANSPOSED repack -> vt[bh][64 e][4096 t], 2 passes
// SOFT=0: fp32 store + bias via padded-LDS float4 repack, 8 passes of 32 rows.
template<int SOFT>
__global__ __launch_bounds__(512, 2) void gemm_bt(
    const unsigned short* __restrict__ A,
    const unsigned short* __restrict__ Bm,
    const float* __restrict__ bias,
    void* __restrict__ C,
    unsigned short* __restrict__ kt,
    unsigned short* __restrict__ vt,
    int M, int N, int K, int ldc)
{
  __shared__ unsigned short sh[24576];       // As 256x64 | Bs 128x64 = 49152 B
  unsigned short* As = sh;
  unsigned short* Bs = sh + 256 * 64;
  const int tid  = threadIdx.x;
  const int wave = tid >> 6;
  const int lane = tid & 63;
  const int quad = lane >> 4;
  const int lr   = lane & 15;
  const int sw7  = lr & 7;
  // XCD swizzle: keep all n-tiles of an m-tile on one XCD (L2 A-reuse)
  const int bid  = ((blockIdx.x & 7) * (gridDim.x >> 3)) + (blockIdx.x >> 3);
  const int nt   = N >> 7;
  const int bn   = (bid % nt) << 7;
  const int bm   = (bid / nt) << 8;
  const int wr   = wave >> 1;                // 4 wave-rows (64 rows each)
  const int wm   = wr << 6;
  const int wn   = (wave & 1) << 6;          // 2 wave-cols

  floatx4 acc[4][4] = {};

  // staging: thread t covers row t/8 (+64 per round), 16B chunk (t&7)^(row&7)
  // (row mod 8 invariant across +64 offsets). LDS stays linear (pre-swizzled src).
  const int srow = tid >> 3;                 // 0..63
  const int scol = ((tid & 7) ^ ((tid >> 3) & 7)) << 3;
  const unsigned short* Ag = A + (size_t)(bm + srow) * K + scol;
  const unsigned short* Bg = Bm + (size_t)(bn + srow) * K + scol;
  unsigned short* Al = As + (wave << 9);     // wave covers rows [wave*8, wave*8+8)
  unsigned short* Bl = Bs + (wave << 9);

  for (int k0 = 0; k0 < K; k0 += 64) {
    __syncthreads();
    gl_lds16(Ag + k0,                     Al);
    gl_lds16(Ag + (size_t)64  * K + k0,   Al + 4096);
    gl_lds16(Ag + (size_t)128 * K + k0,   Al + 8192);
    gl_lds16(Ag + (size_t)192 * K + k0,   Al + 12288);
    gl_lds16(Bg + k0,                     Bl);
    gl_lds16(Bg + (size_t)64  * K + k0,   Bl + 4096);
    __syncthreads();

#pragma unroll
    for (int kk = 0; kk < 2; kk++) {
      const int coff = ((((kk << 2) + quad) ^ sw7) << 3);
      frag8 af[4], bf[4];
#pragma unroll
      for (int i = 0; i < 4; i++)
        af[i] = *(const frag8*)&As[(wm + (i << 4) + lr) * 64 + coff];
#pragma unroll
      for (int j = 0; j < 4; j++)
        bf[j] = *(const frag8*)&Bs[(wn + (j << 4) + lr) * 64 + coff];
#pragma unroll
      for (int i = 0; i < 4; i++)
#pragma unroll
        for (int j = 0; j < 4; j++)
          acc[i][j] = mfma16(af[i], bf[j], acc[i][j]);
    }
  }

  // epilogue: C/D layout col=lane&15, row=quad*4+reg
  const int ccol0 = bn + wn + lr;

#pragma unroll
  for (int j = 0; j < 4; j++) {
    const float bv = bias[ccol0 + (j << 4)];
#pragma unroll
    for (int i = 0; i < 4; i++)
#pragma unroll
      for (int r = 0; r < 4; r++)
        acc[i][j][r] += bv;
  }

  if (SOFT) {
    const int region = bn >> 9;          // 0=q, 1=k, 2=v (block-uniform)
    if (region < 2) {
      // softmax over the 64 cols of this wave's head: 4 j's in-thread + 16 lr lanes
#pragma unroll
      for (int i = 0; i < 4; i++)
#pragma unroll
        for (int r = 0; r < 4; r++) {
          float e0 = __expf(acc[i][0][r]);
          float e1 = __expf(acc[i][1][r]);
          float e2 = __expf(acc[i][2][r]);
          float e3 = __expf(acc[i][3][r]);
          float s = e0 + e1 + e2 + e3;
          s += __shfl_xor(s, 1);
          s += __shfl_xor(s, 2);
          s += __shfl_xor(s, 4);
          s += __shfl_xor(s, 8);
          const float inv = 1.f / s;
          acc[i][0][r] = e0 * inv; acc[i][1][r] = e1 * inv;
          acc[i][2][r] = e2 * inv; acc[i][3][r] = e3 * inv;
        }
    }
    if (region == 0) {
      // q: 4 passes of 64 rows; os[64][132] = 8448 shorts
      unsigned short* os = sh;
#pragma unroll
      for (int p = 0; p < 4; p++) {
        __syncthreads();
        if (wr == p) {
#pragma unroll
          for (int i = 0; i < 4; i++)
#pragma unroll
            for (int j = 0; j < 4; j++)
#pragma unroll
              for (int r = 0; r < 4; r++)
                os[((i << 4) + (quad << 2) + r) * 132 + wn + (j << 4) + lr] = f2b(acc[i][j][r]);
        }
        __syncthreads();
#pragma unroll
        for (int it = 0; it < 2; it++) {
          const int idx = (it << 9) + tid;   // 1024 uint4: 64 rows x 16
          const int row = idx >> 4;
          const int c8  = (idx & 15) << 3;
          *(uint4*)((unsigned short*)C + (size_t)(bm + (p << 6) + row) * ldc + bn + c8) =
              *(const uint4*)&os[row * 132 + c8];
        }
      }
    } else {
      // k/v: transposed store -> T[bh][d][4096 t]. Pass p = head p of this block's
      // 2 heads; waves with wn == p*64 hold it. osT [64 cols][260 stride] (33280 B).
      unsigned short* T = (region == 1) ? kt : vt;
      const int b   = bm >> 12;
      const int tIn = bm & 4095;
      unsigned short* osT = sh;
#pragma unroll
      for (int p = 0; p < 2; p++) {
        __syncthreads();
        if ((wave & 1) == p) {
#pragma unroll
          for (int i = 0; i < 4; i++)
#pragma unroll
            for (int j = 0; j < 4; j++)
#pragma unroll
              for (int r = 0; r < 4; r++)
                osT[((j << 4) + lr) * 260 + wm + (i << 4) + (quad << 2) + r] =
                    f2b(acc[i][j][r]);
        }
        __syncthreads();
        const int hh = ((bn >> 6) + p) & 7;
        unsigned short* Tb = T + (((size_t)(b << 3) + hh) << 18) + tIn;
#pragma unroll
        for (int it = 0; it < 4; it++) {
          const int idx = (it << 9) + tid;   // 2048 uint4: 64 cols x 32 token-groups
          const int col = idx >> 5;          // d
          const int tg  = (idx & 31) << 3;   // 0..255 step 8
          *(uint4*)&Tb[((size_t)col << 12) + tg] = *(const uint4*)&osT[col * 260 + tg];
        }
      }
    }
  } else {
    // fp32 store + bias: 8 passes of 32 rows (32*130 floats = 16640 B)
    float* osf = (float*)sh;
#pragma unroll
    for (int p2 = 0; p2 < 8; p2++) {
      __syncthreads();
      if (wr == (p2 >> 1)) {
#pragma unroll
        for (int i2 = 0; i2 < 2; i2++) {
          const int i = ((p2 & 1) << 1) + i2;
#pragma unroll
          for (int j = 0; j < 4; j++)
#pragma unroll
            for (int r = 0; r < 4; r++)
              osf[((i2 << 4) + (quad << 2) + r) * 130 + wn + (j << 4) + lr] = acc[i][j][r];
        }
      }
      __syncthreads();
#pragma unroll
      for (int it = 0; it < 2; it++) {
        const int idx = (it << 9) + tid;   // 1024 float4: 32 rows x 32
        const int row = idx >> 5;
        const int c4  = (idx & 31) << 2;
        *(float4*)((float*)C +
                   (size_t)(bm + ((p2 >> 1) << 6) + ((p2 & 1) << 5) + row) * ldc + bn + c4) =
            *(const float4*)&osf[row * 130 + c4];
      }
    }
  }
}

// ---------------- kv_context via MFMA: part[chunk][d][e] = sum_t k[t][d] v[t][e] ------------
// kT/vT are [bh][64][4096] (d-major): A = vT rows, B^T = kT rows, both K-contiguous.
// 16 chunks of 256 tokens; each block accumulates 2 sub-tiles of 128 tokens in
// registers (same verified 2-barrier pattern per sub-tile). part layout [d*64+e].
__global__ __launch_bounds__(256) void kv_context(const unsigned short* __restrict__ kt,
                                                  const unsigned short* __restrict__ vt,
                                                  float* __restrict__ part,
                                                  float* __restrict__ ksp) {
  const int bid = blockIdx.x;          // bh(32) x tc(16), tc-fast
  const int tc  = bid & 15;
  const int bh  = bid >> 4;
  __shared__ unsigned short sh[16384]; // vsl[64][128] | ksl[64][128], swizzled
  unsigned short* vsl = sh;
  unsigned short* ksl = sh + 8192;
  const int tid  = threadIdx.x;
  const int wave = tid >> 6;
  const int lane = tid & 63;
  const int quad = lane >> 4;
  const int lr   = lane & 15;

  const int lrow = lane >> 4;
  const int lchk = lane & 15;
  const unsigned short* vg = vt + ((size_t)bh << 18) + (tc << 8);
  const unsigned short* kg = kt + ((size_t)bh << 18) + (tc << 8);

  floatx4 acc[4] = {};
  const int we = wave << 4;
  float s = 0.f;
  const int r2 = tid >> 2;
  const int q4 = tid & 3;

  for (int sub = 0; sub < 2; ++sub) {
    __syncthreads();                    // previous sub-tile's LDS readers done
#pragma unroll
    for (int i = 0; i < 4; i++) {
      const int rb  = (wave << 4) + (i << 2);           // wave-uniform row base
      const int row = rb + lrow;                        // per-lane row
      const int sc  = (lchk ^ (row & 7)) << 3;          // swizzled col (shorts)
      gl_lds16(vg + ((size_t)row << 12) + (sub << 7) + sc, vsl + (rb << 7));
      gl_lds16(kg + ((size_t)row << 12) + (sub << 7) + sc, ksl + (rb << 7));
    }
    __syncthreads();

#pragma unroll
    for (int ks = 0; ks < 4; ks++) {
      const int co = ((((ks << 2) + quad) ^ (lr & 7)) << 3);
      const frag8 af = *(const frag8*)&vsl[(we + lr) * 128 + co];
      frag8 bfr[4];
#pragma unroll
      for (int j = 0; j < 4; j++)
        bfr[j] = *(const frag8*)&ksl[((j << 4) + lr) * 128 + co];
#pragma unroll
      for (int j = 0; j < 4; j++)
        acc[j] = mfma16(af, bfr[j], acc[j]);
    }

    // ksum: row-sums of kT sub-tile (128 t per row), 4 threads per d-row
#pragma unroll
    for (int c = 0; c < 4; c++) {
      const int ch = ((q4 << 2) + c) ^ (r2 & 7);
      const uint4 raw = *(const uint4*)&ksl[r2 * 128 + (ch << 3)];
      s += blo(raw.x) + bhi(raw.x) + blo(raw.y) + bhi(raw.y)
         + blo(raw.z) + bhi(raw.z) + blo(raw.w) + bhi(raw.w);
    }
  }

  // part store: D[e][d] element (lane,j,r): e = we+quad*4+r, d = j*16+lr.
  float* pg = part + ((size_t)(tc * 32 + bh) << 12) + we + (quad << 2);
#pragma unroll
  for (int j = 0; j < 4; j++)
    *(floatx4*)&pg[((j << 4) + lr) << 6] = acc[j];

  s += __shfl_xor(s, 1);
  s += __shfl_xor(s, 2);
  if (q4 == 0) ksp[(tc * 32 + bh) * 64 + r2] = s;
}

// ---------------- reduce partials -> ctxb bf16 [bh][80][64] ----------------
// part rows are d (layout [d][e]); ctxb rows 0-63 = ctxT[e][d] (transposed write),
// row 64 = ksum[d], rows 65-79 = 0.
__global__ __launch_bounds__(256) void ctx_reduce(const float* __restrict__ part,
                                                  const float* __restrict__ ksp,
                                                  unsigned short* __restrict__ ctxb) {
  const int bh = blockIdx.x / 5, g = blockIdx.x % 5;
  const int row = (g << 4) + (threadIdx.x >> 4);    // d for rows<64
  const int d0  = (threadIdx.x & 15) << 2;          // e-range for rows<64
  floatx4 s = {0.f, 0.f, 0.f, 0.f};
  if (row < 64) {
    const float* p = part + ((size_t)bh << 12) + (row << 6) + d0;
    for (int c = 0; c < 16; c++)
      s += *(const floatx4*)(p + ((size_t)c << 17));
#pragma unroll
    for (int i = 0; i < 4; i++)
      ctxb[(size_t)bh * 5120 + ((size_t)(d0 + i) << 6) + row] = f2b(s[i]);
  } else {
    if (row == 64) {
      const float* p = ksp + bh * 64 + d0;
      for (int c = 0; c < 16; c++)
        s += *(const floatx4*)(p + (c << 11));
    }
    ushort4 o;
    o.x = f2b(s.x); o.y = f2b(s.y); o.z = f2b(s.z); o.w = f2b(s.w);
    *(ushort4*)&ctxb[(size_t)bh * 5120 + (row << 6) + d0] = o;
  }
}

// ---------------- attn_out via MFMA: outT[e][t] = ctxT[e][:]·q'[t][:] ----------------
__global__ __launch_bounds__(256) void attn_out(const unsigned short* __restrict__ qb,
                                                const unsigned short* __restrict__ ctxb,
                                                unsigned short* __restrict__ opre) {
  const int tc = blockIdx.x >> 5;      // bh-fast
  const int bh = blockIdx.x & 31;
  const int b = bh >> 3, h = bh & 7;
  const int t0 = b * TT + (tc << 6);
  __shared__ unsigned short sh[144 * 72];   // qs[64][72] | cs[80][72] (cs reused as os)
  unsigned short* qs = sh;
  unsigned short* cs = sh + 64 * 72;
  unsigned short* os = cs;
  const int tid = threadIdx.x;

  for (int i = tid; i < 512; i += 256) {
    const int row = i >> 3, c8 = (i & 7) << 3;
    *(uint4*)&qs[row * 72 + c8] =
        *(const uint4*)&qb[(size_t)(t0 + row) * KDIM + h * 64 + c8];
  }
  for (int i = tid; i < 640; i += 256) {
    const int row = i >> 3, c8 = (i & 7) << 3;
    *(uint4*)&cs[row * 72 + c8] =
        *(const uint4*)&ctxb[(size_t)bh * 5120 + (row << 6) + c8];
  }
  __syncthreads();

  const int lane = tid & 63, w = tid >> 6, quad = lane >> 4, lr = lane & 15;
  floatx4 acc[5] = {};
#pragma unroll
  for (int k2 = 0; k2 < 2; k2++) {
    const int d0 = (k2 << 5) + (quad << 3);
    const frag8 bf = *(const frag8*)&qs[((w << 4) + lr) * 72 + d0];
#pragma unroll
    for (int et = 0; et < 5; et++) {
      const frag8 af = *(const frag8*)&cs[(et * 16 + lr) * 72 + d0];
      acc[et] = mfma16(af, bf, acc[et]);
    }
  }
  const float dinv = 1.f / __shfl(acc[4][0], lr);
  __syncthreads();                      // done reading cs; reuse as os

  const int trow = (w << 4) + lr;
#pragma unroll
  for (int et = 0; et < 4; et++)
#pragma unroll
    for (int r = 0; r < 4; r++) {
      const int e = et * 16 + (quad << 2) + r;
      const float qv = b2f(qs[trow * 72 + e]);
      os[trow * 72 + e] = f2b(acc[et][r] * dinv + qv);
    }
  __syncthreads();

  for (int i = tid; i < 512; i += 256) {
    const int row = i >> 3, c8 = (i & 7) << 3;
    *(uint4*)&opre[(size_t)(t0 + row) * KDIM + h * 64 + c8] = *(const uint4*)&os[row * 72 + c8];
  }
}

// ---------------- launch ----------------
extern "C" void kernel_launch(void* const* d_in, const int* in_sizes, int n_in,
                              void* d_out, int out_size, void* d_ws, size_t ws_size,
                              hipStream_t stream) {
  (void)in_sizes; (void)n_in; (void)out_size; (void)ws_size;
  const float* x  = (const float*)d_in[0];
  const float* Wq = (const float*)d_in[1];
  const float* bq = (const float*)d_in[2];
  const float* Wk = (const float*)d_in[3];
  const float* bk = (const float*)d_in[4];
  const float* Wv = (const float*)d_in[5];
  const float* bv = (const float*)d_in[6];
  const float* Wp = (const float*)d_in[7];
  const float* bp = (const float*)d_in[8];

  char* w = (char*)d_ws;
  unsigned short* xb   = (unsigned short*)w; w += (size_t)NTOK * KDIM * 2;   // 16 MB
  float* part          = (float*)xb;         // alias: xb dead after qkv GEMM
  unsigned short* wqkv = (unsigned short*)w; w += (size_t)NQKV * KDIM * 2;   // 1.5 MB
  unsigned short* wp   = (unsigned short*)w; w += (size_t)KDIM * KDIM * 2;   // 0.5 MB
  float* bias_qkv      = (float*)w;          w += (size_t)NQKV * 4;          // 6 KB
  float* ksp           = (float*)w;          w += (size_t)1024 * 64 * 4;     // 256 KB
  unsigned short* ctxb = (unsigned short*)w; w += (size_t)32 * 80 * 64 * 2;  // 320 KB
  unsigned short* qkv  = (unsigned short*)w; w += (size_t)NTOK * NQKV * 2;   // 48 MB
  unsigned short* opre = (unsigned short*)w; w += (size_t)NTOK * KDIM * 2;   // 16 MB

  unsigned short* qb  = qkv;                               // 16 MB [t][512]
  unsigned short* ktb = qkv + (size_t)NTOK * 512;          // 16 MB [bh][64][4096]
  unsigned short* vtb = ktb + (size_t)32 * 64 * TT;        // 16 MB [bh][64][4096]

  cvt_all<<<9222, 256, 0, stream>>>(x, Wq, Wk, Wv, Wp, bq, bk, bv,
                                    xb, wqkv, wp, bias_qkv);
  // BM=256, BN=128: grid 64x12 = 768 = 3.0 exact rounds on 256 CUs (768 % 8 == 0)
  gemm_bt<1><<<(NTOK / 256) * (NQKV / 128), 512, 0, stream>>>(
      xb, wqkv, bias_qkv, qb, ktb, vtb, NTOK, NQKV, KDIM, 512);
  kv_context<<<512, 256, 0, stream>>>(ktb, vtb, part, ksp);
  ctx_reduce<<<160, 256, 0, stream>>>(part, ksp, ctxb);
  attn_out<<<2048, 256, 0, stream>>>(qb, ctxb, opre);
  // BM=256, BN=128: grid 64x4 = 256 = 1.0 exact round
  gemm_bt<0><<<(NTOK / 256) * (KDIM / 128), 512, 0, stream>>>(
      opre, wp, bp, d_out, nullptr, nullptr, NTOK, KDIM, KDIM, KDIM);
}

// Round 10
// 172.368 us; speedup vs baseline: 1.0216x; 1.0216x over previous
//
#include <hip/hip_runtime.h>

#define NTOK  16384   // B*T
#define KDIM  512
#define NQKV  1536
#define TT    4096

using frag8   = __attribute__((ext_vector_type(8))) short;
using floatx4 = __attribute__((ext_vector_type(4))) float;

__device__ __forceinline__ unsigned short f2b(float f) {
  union { float f; unsigned u; } v; v.f = f;
  unsigned r = v.u + 0x7fffu + ((v.u >> 16) & 1u);
  return (unsigned short)(r >> 16);
}
__device__ __forceinline__ float b2f(unsigned short s) {
  union { unsigned u; float f; } v; v.u = ((unsigned)s) << 16; return v.f;
}
__device__ __forceinline__ float blo(unsigned w) {
  union { unsigned u; float f; } v; v.u = w << 16; return v.f;
}
__device__ __forceinline__ float bhi(unsigned w) {
  union { unsigned u; float f; } v; v.u = w & 0xffff0000u; return v.f;
}

__device__ __forceinline__ void gl_lds16(const void* g, void* l) {
  __builtin_amdgcn_global_load_lds((__attribute__((address_space(1))) const void*)g,
                                   (__attribute__((address_space(3))) void*)l,
                                   16, 0, 0);
}
__device__ __forceinline__ floatx4 mfma16(frag8 a, frag8 b, floatx4 c) {
  return __builtin_amdgcn_mfma_f32_16x16x32_bf16(a, b, c, 0, 0, 0);
}

// ---------------- fused convert: x -> bf16, weights -> bf16 (float4), bias concat --------
__global__ __launch_bounds__(256) void cvt_all(
    const float* __restrict__ x,
    const float* __restrict__ Wq, const float* __restrict__ Wk,
    const float* __restrict__ Wv, const float* __restrict__ Wp,
    const float* __restrict__ bq, const float* __restrict__ bk,
    const float* __restrict__ bv,
    unsigned short* __restrict__ xb,
    unsigned short* __restrict__ wqkv, unsigned short* __restrict__ wp,
    float* __restrict__ bias_qkv) {
  const int blk = blockIdx.x;
  if (blk < 8192) {                          // x: 8.4M floats, float4 per thread
    const size_t i = (size_t)blk * 256 + threadIdx.x;
    const float4 v = ((const float4*)x)[i];
    ushort4 o;
    o.x = f2b(v.x); o.y = f2b(v.y); o.z = f2b(v.z); o.w = f2b(v.w);
    ((ushort4*)xb)[i] = o;
    return;
  }
  int idx = (blk - 8192) * 256 + threadIdx.x;
  if (idx < 196608) {                       // wqkv: 1536 rows x 128 float4
    const int m = idx >> 7, c4 = (idx & 127) << 2;
    const float* W = (m < 512) ? Wq : ((m < 1024) ? Wk : Wv);
    const float4 v = *(const float4*)&W[(m & 511) * 512 + c4];
    ushort4 o;
    o.x = f2b(v.x); o.y = f2b(v.y); o.z = f2b(v.z); o.w = f2b(v.w);
    *(ushort4*)&wqkv[m * 512 + c4] = o;
    return;
  }
  idx -= 196608;
  if (idx < 65536) {                        // wp: 65536 float4
    const float4 v = ((const float4*)Wp)[idx];
    ushort4 o;
    o.x = f2b(v.x); o.y = f2b(v.y); o.z = f2b(v.z); o.w = f2b(v.w);
    ((ushort4*)wp)[idx] = o;
    return;
  }
  idx -= 65536;
  if (idx < 1536)
    bias_qkv[idx] = (idx < 512) ? bq[idx]
                  : ((idx < 1024) ? bk[idx - 512] : bv[idx - 1024]);
}

// ---------------- bf16 GEMM, B^T input, XCD-swizzled, BK=64 + XOR LDS swizzle ----------------
// Verified round-0 K-loop (128x128 tile, 4 waves, single-buffered staging, __syncthreads).
// LDS capped at exactly 32 KB (fp32 repack runs in 4 passes of 32 rows).
// SOFT=1 epilogue by region (block-uniform, 512%128==0):
//   region 0 (q): softmax + padded-LDS repack -> C (q_buf, ldc=512)
//   region 1 (k): softmax + TRANSPOSED repack -> kt[bh][64 d][4096 t]
//   region 2 (v): TRANSPOSED repack -> vt[bh][64 e][4096 t]
// SOFT=0: fp32 store + bias via padded-LDS float4 repack (4 passes).
template<int SOFT>
__global__ __launch_bounds__(256, 2) void gemm_bt(
    const unsigned short* __restrict__ A,
    const unsigned short* __restrict__ Bm,
    const float* __restrict__ bias,
    void* __restrict__ C,
    unsigned short* __restrict__ kt,
    unsigned short* __restrict__ vt,
    int M, int N, int K, int ldc)
{
  __shared__ unsigned short sh[16384];       // 32768 B: staging; epilogue reuses low region
  unsigned short* As = sh;
  unsigned short* Bs = sh + 128 * 64;
  const int tid  = threadIdx.x;
  const int wave = tid >> 6;
  const int lane = tid & 63;
  const int quad = lane >> 4;
  const int lr   = lane & 15;
  const int sw7  = lr & 7;
  // XCD swizzle: keep all n-tiles of an m-tile on one XCD (L2 A-reuse)
  const int bid  = ((blockIdx.x & 7) * (gridDim.x >> 3)) + (blockIdx.x >> 3);
  const int nt   = N >> 7;
  const int bn   = (bid % nt) << 7;
  const int bm   = (bid / nt) << 7;
  const int half = wave >> 1;
  const int wm   = half << 6;
  const int wn   = (wave & 1) << 6;

  floatx4 acc[4][4] = {};

  const int srow = tid >> 3;
  const int scol = ((tid & 7) ^ ((tid >> 3) & 7)) << 3;
  const unsigned short* Ag = A + (size_t)(bm + srow) * K + scol;
  const unsigned short* Bg = Bm + (size_t)(bn + srow) * K + scol;
  unsigned short* Al = As + (wave << 9);
  unsigned short* Bl = Bs + (wave << 9);

  for (int k0 = 0; k0 < K; k0 += 64) {
    __syncthreads();
    gl_lds16(Ag + k0,                    Al);
    gl_lds16(Ag + (size_t)32 * K + k0,   Al + 2048);
    gl_lds16(Ag + (size_t)64 * K + k0,   Al + 4096);
    gl_lds16(Ag + (size_t)96 * K + k0,   Al + 6144);
    gl_lds16(Bg + k0,                    Bl);
    gl_lds16(Bg + (size_t)32 * K + k0,   Bl + 2048);
    gl_lds16(Bg + (size_t)64 * K + k0,   Bl + 4096);
    gl_lds16(Bg + (size_t)96 * K + k0,   Bl + 6144);
    __syncthreads();

#pragma unroll
    for (int kk = 0; kk < 2; kk++) {
      const int coff = ((((kk << 2) + quad) ^ sw7) << 3);
      frag8 af[4], bf[4];
#pragma unroll
      for (int i = 0; i < 4; i++)
        af[i] = *(const frag8*)&As[(wm + (i << 4) + lr) * 64 + coff];
#pragma unroll
      for (int j = 0; j < 4; j++)
        bf[j] = *(const frag8*)&Bs[(wn + (j << 4) + lr) * 64 + coff];
#pragma unroll
      for (int i = 0; i < 4; i++)
#pragma unroll
        for (int j = 0; j < 4; j++)
          acc[i][j] = mfma16(af[i], bf[j], acc[i][j]);
    }
  }

  // epilogue: C/D layout col=lane&15, row=quad*4+reg
  const int ccol0 = bn + wn + lr;

#pragma unroll
  for (int j = 0; j < 4; j++) {
    const float bv = bias[ccol0 + (j << 4)];
#pragma unroll
    for (int i = 0; i < 4; i++)
#pragma unroll
      for (int r = 0; r < 4; r++)
        acc[i][j][r] += bv;
  }

  if (SOFT) {
    const int region = bn >> 9;          // 0=q, 1=k, 2=v (block-uniform: 512 % 128 == 0)
    if (region < 2) {
#pragma unroll
      for (int i = 0; i < 4; i++)
#pragma unroll
        for (int r = 0; r < 4; r++) {
          float e0 = __expf(acc[i][0][r]);
          float e1 = __expf(acc[i][1][r]);
          float e2 = __expf(acc[i][2][r]);
          float e3 = __expf(acc[i][3][r]);
          float s = e0 + e1 + e2 + e3;
          s += __shfl_xor(s, 1);
          s += __shfl_xor(s, 2);
          s += __shfl_xor(s, 4);
          s += __shfl_xor(s, 8);
          const float inv = 1.f / s;
          acc[i][0][r] = e0 * inv; acc[i][1][r] = e1 * inv;
          acc[i][2][r] = e2 * inv; acc[i][3][r] = e3 * inv;
        }
    }
    if (region == 0) {
      // q: coalesced bf16 store via padded LDS repack (stride 132), ldc = 512
      unsigned short* os = sh;
#pragma unroll
      for (int p = 0; p < 2; p++) {
        __syncthreads();
        if (half == p) {
#pragma unroll
          for (int i = 0; i < 4; i++)
#pragma unroll
            for (int j = 0; j < 4; j++)
#pragma unroll
              for (int r = 0; r < 4; r++)
                os[((i << 4) + (quad << 2) + r) * 132 + wn + (j << 4) + lr] = f2b(acc[i][j][r]);
        }
        __syncthreads();
#pragma unroll
        for (int it = 0; it < 4; it++) {
          const int idx = (it << 8) + tid;   // 1024 uint4 total
          const int row = idx >> 4;
          const int c8  = (idx & 15) << 3;
          *(uint4*)((unsigned short*)C + (size_t)(bm + (p << 6) + row) * ldc + bn + c8) =
              *(const uint4*)&os[row * 132 + c8];
        }
      }
    } else {
      // k/v: transposed store -> T[bh][d][4096 t]. Pass p handles the 64 cols of
      // waves with wn == p*64 (one head exactly). osT [64 cols][130 rows-stride].
      unsigned short* T = (region == 1) ? kt : vt;
      const int b   = bm >> 12;
      const int tIn = bm & 4095;
      unsigned short* osT = sh;
#pragma unroll
      for (int p = 0; p < 2; p++) {
        __syncthreads();
        if ((wave & 1) == p) {
#pragma unroll
          for (int i = 0; i < 4; i++)
#pragma unroll
            for (int j = 0; j < 4; j++)
#pragma unroll
              for (int r = 0; r < 4; r++)
                osT[((j << 4) + lr) * 130 + wm + (i << 4) + (quad << 2) + r] =
                    f2b(acc[i][j][r]);
        }
        __syncthreads();
        const int hh = ((bn >> 6) + p) & 7;
        unsigned short* Tb = T + (((size_t)(b << 3) + hh) << 18) + tIn;
#pragma unroll
        for (int it = 0; it < 4; it++) {
          const int idx = (it << 8) + tid;   // 1024 uint4: 64 cols x 16 token-groups
          const int col = idx >> 4;          // d
          const int tg  = (idx & 15) << 3;
          *(uint4*)&Tb[((size_t)col << 12) + tg] = *(const uint4*)&osT[col * 130 + tg];
        }
      }
    }
  } else {
    // fp32 store + bias: 4 passes of 32 rows (32*130 floats = 16640 B <= 32 KB)
    float* osf = (float*)sh;
#pragma unroll
    for (int p2 = 0; p2 < 4; p2++) {
      __syncthreads();
      if (half == (p2 >> 1)) {
#pragma unroll
        for (int i2 = 0; i2 < 2; i2++) {
          const int i = ((p2 & 1) << 1) + i2;
#pragma unroll
          for (int j = 0; j < 4; j++)
#pragma unroll
            for (int r = 0; r < 4; r++)
              osf[((i2 << 4) + (quad << 2) + r) * 130 + wn + (j << 4) + lr] = acc[i][j][r];
        }
      }
      __syncthreads();
#pragma unroll
      for (int it = 0; it < 4; it++) {
        const int idx = (it << 8) + tid;   // 1024 float4: 32 rows x 32 float4
        const int row = idx >> 5;
        const int c4  = (idx & 31) << 2;
        *(float4*)((float*)C +
                   (size_t)(bm + ((p2 >> 1) << 6) + ((p2 & 1) << 5) + row) * ldc + bn + c4) =
            *(const float4*)&osf[row * 130 + c4];
      }
    }
  }
}

// ---------------- kv_context via MFMA: part[chunk][d][e] = sum_t k[t][d] v[t][e] ------------
// kT/vT are [bh][64][4096] (d-major): A = vT rows, B^T = kT rows, both K-contiguous.
// 16 chunks of 256 tokens; each block accumulates 2 sub-tiles of 128 tokens in
// registers (same verified 2-barrier pattern per sub-tile). part layout [d*64+e].
__global__ __launch_bounds__(256) void kv_context(const unsigned short* __restrict__ kt,
                                                  const unsigned short* __restrict__ vt,
                                                  float* __restrict__ part,
                                                  float* __restrict__ ksp) {
  const int bid = blockIdx.x;          // bh(32) x tc(16), tc-fast
  const int tc  = bid & 15;
  const int bh  = bid >> 4;
  __shared__ unsigned short sh[16384]; // vsl[64][128] | ksl[64][128], swizzled
  unsigned short* vsl = sh;
  unsigned short* ksl = sh + 8192;
  const int tid  = threadIdx.x;
  const int wave = tid >> 6;
  const int lane = tid & 63;
  const int quad = lane >> 4;
  const int lr   = lane & 15;

  const int lrow = lane >> 4;
  const int lchk = lane & 15;
  const unsigned short* vg = vt + ((size_t)bh << 18) + (tc << 8);
  const unsigned short* kg = kt + ((size_t)bh << 18) + (tc << 8);

  floatx4 acc[4] = {};
  const int we = wave << 4;
  float s = 0.f;
  const int r2 = tid >> 2;
  const int q4 = tid & 3;

  for (int sub = 0; sub < 2; ++sub) {
    __syncthreads();                    // previous sub-tile's LDS readers done
#pragma unroll
    for (int i = 0; i < 4; i++) {
      const int rb  = (wave << 4) + (i << 2);           // wave-uniform row base
      const int row = rb + lrow;                        // per-lane row
      const int sc  = (lchk ^ (row & 7)) << 3;          // swizzled col (shorts)
      gl_lds16(vg + ((size_t)row << 12) + (sub << 7) + sc, vsl + (rb << 7));
      gl_lds16(kg + ((size_t)row << 12) + (sub << 7) + sc, ksl + (rb << 7));
    }
    __syncthreads();

#pragma unroll
    for (int ks = 0; ks < 4; ks++) {
      const int co = ((((ks << 2) + quad) ^ (lr & 7)) << 3);
      const frag8 af = *(const frag8*)&vsl[(we + lr) * 128 + co];
      frag8 bfr[4];
#pragma unroll
      for (int j = 0; j < 4; j++)
        bfr[j] = *(const frag8*)&ksl[((j << 4) + lr) * 128 + co];
#pragma unroll
      for (int j = 0; j < 4; j++)
        acc[j] = mfma16(af, bfr[j], acc[j]);
    }

    // ksum: row-sums of kT sub-tile (128 t per row), 4 threads per d-row
#pragma unroll
    for (int c = 0; c < 4; c++) {
      const int ch = ((q4 << 2) + c) ^ (r2 & 7);
      const uint4 raw = *(const uint4*)&ksl[r2 * 128 + (ch << 3)];
      s += blo(raw.x) + bhi(raw.x) + blo(raw.y) + bhi(raw.y)
         + blo(raw.z) + bhi(raw.z) + blo(raw.w) + bhi(raw.w);
    }
  }

  // part store: D[e][d] element (lane,j,r): e = we+quad*4+r, d = j*16+lr.
  float* pg = part + ((size_t)(tc * 32 + bh) << 12) + we + (quad << 2);
#pragma unroll
  for (int j = 0; j < 4; j++)
    *(floatx4*)&pg[((j << 4) + lr) << 6] = acc[j];

  s += __shfl_xor(s, 1);
  s += __shfl_xor(s, 2);
  if (q4 == 0) ksp[(tc * 32 + bh) * 64 + r2] = s;
}

// ---------------- reduce partials -> ctxb bf16 [bh][80][64] ----------------
// part rows are d (layout [d][e]); ctxb rows 0-63 = ctxT[e][d] (transposed write),
// row 64 = ksum[d], rows 65-79 = 0.
__global__ __launch_bounds__(256) void ctx_reduce(const float* __restrict__ part,
                                                  const float* __restrict__ ksp,
                                                  unsigned short* __restrict__ ctxb) {
  const int bh = blockIdx.x / 5, g = blockIdx.x % 5;
  const int row = (g << 4) + (threadIdx.x >> 4);    // d for rows<64
  const int d0  = (threadIdx.x & 15) << 2;          // e-range for rows<64
  floatx4 s = {0.f, 0.f, 0.f, 0.f};
  if (row < 64) {
    const float* p = part + ((size_t)bh << 12) + (row << 6) + d0;
    for (int c = 0; c < 16; c++)
      s += *(const floatx4*)(p + ((size_t)c << 17));
#pragma unroll
    for (int i = 0; i < 4; i++)
      ctxb[(size_t)bh * 5120 + ((size_t)(d0 + i) << 6) + row] = f2b(s[i]);
  } else {
    if (row == 64) {
      const float* p = ksp + bh * 64 + d0;
      for (int c = 0; c < 16; c++)
        s += *(const floatx4*)(p + (c << 11));
    }
    ushort4 o;
    o.x = f2b(s.x); o.y = f2b(s.y); o.z = f2b(s.z); o.w = f2b(s.w);
    *(ushort4*)&ctxb[(size_t)bh * 5120 + (row << 6) + d0] = o;
  }
}

// ---------------- attn_out via MFMA: outT[e][t] = ctxT[e][:]·q'[t][:] ----------------
__global__ __launch_bounds__(256) void attn_out(const unsigned short* __restrict__ qb,
                                                const unsigned short* __restrict__ ctxb,
                                                unsigned short* __restrict__ opre) {
  const int tc = blockIdx.x >> 5;      // bh-fast
  const int bh = blockIdx.x & 31;
  const int b = bh >> 3, h = bh & 7;
  const int t0 = b * TT + (tc << 6);
  __shared__ unsigned short sh[144 * 72];   // qs[64][72] | cs[80][72] (cs reused as os)
  unsigned short* qs = sh;
  unsigned short* cs = sh + 64 * 72;
  unsigned short* os = cs;
  const int tid = threadIdx.x;

  for (int i = tid; i < 512; i += 256) {
    const int row = i >> 3, c8 = (i & 7) << 3;
    *(uint4*)&qs[row * 72 + c8] =
        *(const uint4*)&qb[(size_t)(t0 + row) * KDIM + h * 64 + c8];
  }
  for (int i = tid; i < 640; i += 256) {
    const int row = i >> 3, c8 = (i & 7) << 3;
    *(uint4*)&cs[row * 72 + c8] =
        *(const uint4*)&ctxb[(size_t)bh * 5120 + (row << 6) + c8];
  }
  __syncthreads();

  const int lane = tid & 63, w = tid >> 6, quad = lane >> 4, lr = lane & 15;
  floatx4 acc[5] = {};
#pragma unroll
  for (int k2 = 0; k2 < 2; k2++) {
    const int d0 = (k2 << 5) + (quad << 3);
    const frag8 bf = *(const frag8*)&qs[((w << 4) + lr) * 72 + d0];
#pragma unroll
    for (int et = 0; et < 5; et++) {
      const frag8 af = *(const frag8*)&cs[(et * 16 + lr) * 72 + d0];
      acc[et] = mfma16(af, bf, acc[et]);
    }
  }
  const float dinv = 1.f / __shfl(acc[4][0], lr);
  __syncthreads();                      // done reading cs; reuse as os

  const int trow = (w << 4) + lr;
#pragma unroll
  for (int et = 0; et < 4; et++)
#pragma unroll
    for (int r = 0; r < 4; r++) {
      const int e = et * 16 + (quad << 2) + r;
      const float qv = b2f(qs[trow * 72 + e]);
      os[trow * 72 + e] = f2b(acc[et][r] * dinv + qv);
    }
  __syncthreads();

  for (int i = tid; i < 512; i += 256) {
    const int row = i >> 3, c8 = (i & 7) << 3;
    *(uint4*)&opre[(size_t)(t0 + row) * KDIM + h * 64 + c8] = *(const uint4*)&os[row * 72 + c8];
  }
}

// ---------------- launch ----------------
extern "C" void kernel_launch(void* const* d_in, const int* in_sizes, int n_in,
                              void* d_out, int out_size, void* d_ws, size_t ws_size,
                              hipStream_t stream) {
  (void)in_sizes; (void)n_in; (void)out_size; (void)ws_size;
  const float* x  = (const float*)d_in[0];
  const float* Wq = (const float*)d_in[1];
  const float* bq = (const float*)d_in[2];
  const float* Wk = (const float*)d_in[3];
  const float* bk = (const float*)d_in[4];
  const float* Wv = (const float*)d_in[5];
  const float* bv = (const float*)d_in[6];
  const float* Wp = (const float*)d_in[7];
  const float* bp = (const float*)d_in[8];

  char* w = (char*)d_ws;
  unsigned short* xb   = (unsigned short*)w; w += (size_t)NTOK * KDIM * 2;   // 16 MB
  float* part          = (float*)xb;         // alias: xb dead after qkv GEMM
  unsigned short* wqkv = (unsigned short*)w; w += (size_t)NQKV * KDIM * 2;   // 1.5 MB
  unsigned short* wp   = (unsigned short*)w; w += (size_t)KDIM * KDIM * 2;   // 0.5 MB
  float* bias_qkv      = (float*)w;          w += (size_t)NQKV * 4;          // 6 KB
  float* ksp           = (float*)w;          w += (size_t)1024 * 64 * 4;     // 256 KB
  unsigned short* ctxb = (unsigned short*)w; w += (size_t)32 * 80 * 64 * 2;  // 320 KB
  unsigned short* qkv  = (unsigned short*)w; w += (size_t)NTOK * NQKV * 2;   // 48 MB
  unsigned short* opre = (unsigned short*)w; w += (size_t)NTOK * KDIM * 2;   // 16 MB

  unsigned short* qb  = qkv;                               // 16 MB [t][512]
  unsigned short* ktb = qkv + (size_t)NTOK * 512;          // 16 MB [bh][64][4096]
  unsigned short* vtb = ktb + (size_t)32 * 64 * TT;        // 16 MB [bh][64][4096]

  cvt_all<<<9222, 256, 0, stream>>>(x, Wq, Wk, Wv, Wp, bq, bk, bv,
                                    xb, wqkv, wp, bias_qkv);
  gemm_bt<1><<<(NTOK / 128) * (NQKV / 128), 256, 0, stream>>>(
      xb, wqkv, bias_qkv, qb, ktb, vtb, NTOK, NQKV, KDIM, 512);
  kv_context<<<512, 256, 0, stream>>>(ktb, vtb, part, ksp);
  ctx_reduce<<<160, 256, 0, stream>>>(part, ksp, ctxb);
  attn_out<<<2048, 256, 0, stream>>>(qb, ctxb, opre);
  gemm_bt<0><<<(NTOK / 128) * (KDIM / 128), 256, 0, stream>>>(
      opre, wp, bp, d_out, nullptr, nullptr, NTOK, KDIM, KDIM, KDIM);
}